// Round 5
// baseline (75.303 us; speedup 1.0000x reference)
//
#include <hip/hip_runtime.h>
#include <hip/hip_bf16.h>

// NonlocalBlock2D: B=2, C=64, IC=32, H=W=96, N=9216.
// o = Wo @ softmax(theta^T phi) @ g + bo + x  (all 1x1 convs == channel GEMMs)
//
// Round-5: attn waves own 32 queries (2 Q-fragments) so each K/V LDS tile read
// serves 2x the scores (LDS pipe was the measured bottleneck); V stored in
// globally pre-permuted key order so PV reads are 4x ds_read_b128; proj/out
// restructured to cut their x/Y re-read traffic (151MB->19MB, 38MB->19MB).

#define B_   2
#define C_   64
#define IC_  32
#define N_   9216
#define SEG_       8
#define SEG_KEYS   1152
#define SEG_TILES  18      // SEG_KEYS / 64
#define QBLK128    72      // N_/128
#define LOG2E 1.44269504088896f

typedef __attribute__((ext_vector_type(4))) float  f32x4;
typedef __attribute__((ext_vector_type(8))) short  s16x8;
typedef __attribute__((ext_vector_type(4))) short  s16x4;

static __device__ __forceinline__ ushort f2bf(float f) {
  union { __hip_bfloat16 h; ushort u; } cv;
  cv.h = __float2bfloat16(f);
  return cv.u;
}

static __device__ __forceinline__ float bf2f(ushort u) {
  union { uint i; float f; } c;
  c.i = ((uint)u) << 16;
  return c.f;
}

static __device__ __forceinline__ f32x4 mfma32(s16x8 a, s16x8 b, f32x4 c) {
  return __builtin_amdgcn_mfma_f32_16x16x32_bf16(a, b, c, 0, 0, 0);
}

// ---------------------------------------------------------------------------
// Kernel 1: projections. theta*log2e->Q[B][N][32], phi->K[B][N][32],
// g->Vt[B][32][N] with keys PERMUTED within each 64-tile:
//   j=n&63, u=j>>5, r=j&31 -> pos = u*32 + (r&15)*2 + (r>>4)
// (so attn PV half-fragments are contiguous 16B). Any within-64 permutation
// preserves store coalescing (same cachelines).
// grid: 4 ic-groups x 72 n-blocks = 288 blocks, 256 thr. Thread: 8 ic, 1 n.
// ---------------------------------------------------------------------------
__global__ __launch_bounds__(256) void proj_kernel(
    const float* __restrict__ x,
    const float* __restrict__ Wg, const float* __restrict__ bg,
    const float* __restrict__ Wt, const float* __restrict__ bt,
    const float* __restrict__ Wp, const float* __restrict__ bp,
    ushort* __restrict__ Qb, ushort* __restrict__ Kb, ushort* __restrict__ Vt)
{
  const int grp = blockIdx.x / 72;          // 0..3 (wave-uniform)
  const int ic0 = grp * 8;
  const int bn  = (blockIdx.x % 72) * 256 + threadIdx.x;
  const int b   = bn / N_;
  const int n   = bn % N_;

  float ag[8], at_[8], ap[8];
#pragma unroll
  for (int j = 0; j < 8; ++j) { ag[j] = 0.f; at_[j] = 0.f; ap[j] = 0.f; }

  const float* xp = x + (size_t)b * C_ * N_ + n;
#pragma unroll 8
  for (int c = 0; c < C_; ++c) {
    const float xv = xp[(size_t)c * N_];
#pragma unroll
    for (int j = 0; j < 8; ++j) {
      ag[j]  = fmaf(Wg[(ic0 + j) * C_ + c], xv, ag[j]);
      at_[j] = fmaf(Wt[(ic0 + j) * C_ + c], xv, at_[j]);
      ap[j]  = fmaf(Wp[(ic0 + j) * C_ + c], xv, ap[j]);
    }
  }

  // permuted key position for V
  const int j6 = n & 63, u = j6 >> 5, r = j6 & 31;
  const int nperm = (n - j6) + u * 32 + (r & 15) * 2 + (r >> 4);

#pragma unroll
  for (int j = 0; j < 8; ++j) {
    const int ic = ic0 + j;
    Qb[(size_t)bn * IC_ + ic] = f2bf(LOG2E * (at_[j] + bt[ic]));  // exp2 domain
    Kb[(size_t)bn * IC_ + ic] = f2bf(ap[j] + bp[ic]);
    Vt[(size_t)(b * IC_ + ic) * N_ + nperm] = f2bf(ag[j] + bg[ic]);
  }
}

// ---------------------------------------------------------------------------
// Kernel 2: flash attention over ONE KV segment (1152 keys, 18 tiles of 64).
// block = 4 waves x 32 queries = 128 q. Each wave holds TWO Q-fragments
// (qbaseA rows, qbaseB=+16) so every K/V LDS tile read serves both.
// Swapped QK^T: mfma(K,Q); sX0[i]=S'[key u*32+4h+i], sX1[i]=S'[+16].
// p=exp2(S') (bounded, no max); PV B-operand = V read as ONE b128 thanks to
// the global key permutation; pa packed interleaved (us[2i]=lo-half,
// us[2i+1]=hi-half) to match. Denominator via ones-MFMA. 
// ---------------------------------------------------------------------------
__global__ __launch_bounds__(256, 4) void attn_kernel(
    const ushort* __restrict__ Qb, const ushort* __restrict__ Kb,
    const ushort* __restrict__ Vt, ushort* __restrict__ Opart,
    float* __restrict__ Lp)
{
  __shared__ __align__(16) ushort Kl[64 * 40];  // 64 keys x 32 d, stride 40
  __shared__ __align__(16) ushort Vl[32 * 70];  // 32 d x 64 keys (perm'd), stride 70

  const int qblk = blockIdx.x % QBLK128;
  const int bs   = blockIdx.x / QBLK128;   // b*SEG_ + seg
  const int seg  = bs & (SEG_ - 1);
  const int b    = bs >> 3;
  const int key0 = seg * SEG_KEYS;

  const int tid  = threadIdx.x;
  const int lane = tid & 63;
  const int wave = tid >> 6;
  const int q16  = lane & 15;
  const int h    = lane >> 4;

  const int qbaseA = qblk * 128 + wave * 32;
  const int qbaseB = qbaseA + 16;

  const short ONE = (short)0x3F80;
  const s16x8 ones = {ONE, ONE, ONE, ONE, ONE, ONE, ONE, ONE};

  const s16x8 qfragA = *reinterpret_cast<const s16x8*>(
      Qb + (size_t)(b * N_ + qbaseA + q16) * IC_ + h * 8);
  const s16x8 qfragB = *reinterpret_cast<const s16x8*>(
      Qb + (size_t)(b * N_ + qbaseB + q16) * IC_ + h * 8);

  f32x4 aA0 = {0.f,0.f,0.f,0.f}, aA1 = {0.f,0.f,0.f,0.f}, aLA = {0.f,0.f,0.f,0.f};
  f32x4 aB0 = {0.f,0.f,0.f,0.f}, aB1 = {0.f,0.f,0.f,0.f}, aLB = {0.f,0.f,0.f,0.f};

  // staging: K tile 64x32x2B = 4KB = 256 x 16B chunks (1/thread); V same.
  const int krow = tid >> 2, kpart = tid & 3;
  const ushort* kg = Kb + ((size_t)b * N_ + key0 + krow) * IC_ + kpart * 8;
  ushort* kl_dst = &Kl[krow * 40 + kpart * 8];

  const int vd = tid >> 3, vp = tid & 7;
  const ushort* vg = Vt + (size_t)(b * IC_ + vd) * N_ + key0 + vp * 8;
  ushort* vl_dst = &Vl[vd * 70 + vp * 8];

  s16x8 kreg = *reinterpret_cast<const s16x8*>(kg);
  s16x8 vreg = *reinterpret_cast<const s16x8*>(vg);

  for (int it = 0; it < SEG_TILES; ++it) {
    *reinterpret_cast<s16x8*>(kl_dst) = kreg;
    *reinterpret_cast<s16x8*>(vl_dst) = vreg;
    __syncthreads();

    if (it + 1 < SEG_TILES) {
      kg += 64 * IC_;
      vg += 64;
      kreg = *reinterpret_cast<const s16x8*>(kg);
      vreg = *reinterpret_cast<const s16x8*>(vg);
    }

#pragma unroll
    for (int u = 0; u < 2; ++u) {
      const s16x8 kf0 = *reinterpret_cast<const s16x8*>(&Kl[(u * 32 + q16) * 40 + h * 8]);
      const s16x8 kf1 = *reinterpret_cast<const s16x8*>(&Kl[(u * 32 + 16 + q16) * 40 + h * 8]);
      const f32x4 z = {0.f, 0.f, 0.f, 0.f};
      const f32x4 sA0 = mfma32(kf0, qfragA, z);
      const f32x4 sA1 = mfma32(kf1, qfragA, z);
      const f32x4 sB0 = mfma32(kf0, qfragB, z);
      const f32x4 sB1 = mfma32(kf1, qfragB, z);

      const s16x8 vf0 = *reinterpret_cast<const s16x8*>(&Vl[q16 * 70 + u * 32 + h * 8]);
      const s16x8 vf1 = *reinterpret_cast<const s16x8*>(&Vl[(16 + q16) * 70 + u * 32 + h * 8]);

      union { ushort us[8]; s16x8 v; } paA, paB;
#pragma unroll
      for (int i = 0; i < 4; ++i) {
        paA.us[2 * i]     = f2bf(__builtin_amdgcn_exp2f(sA0[i]));
        paA.us[2 * i + 1] = f2bf(__builtin_amdgcn_exp2f(sA1[i]));
        paB.us[2 * i]     = f2bf(__builtin_amdgcn_exp2f(sB0[i]));
        paB.us[2 * i + 1] = f2bf(__builtin_amdgcn_exp2f(sB1[i]));
      }
      aA0 = mfma32(paA.v, vf0, aA0);
      aA1 = mfma32(paA.v, vf1, aA1);
      aLA = mfma32(paA.v, ones, aLA);
      aB0 = mfma32(paB.v, vf0, aB0);
      aB1 = mfma32(paB.v, vf1, aB1);
      aLB = mfma32(paB.v, ones, aLB);
    }
    __syncthreads();
  }

  // store partial O (bf16, unnormalized) and partial l (from ones-MFMA)
  const size_t obase0 = ((size_t)(b * SEG_ + seg) * N_);
#pragma unroll
  for (int r = 0; r < 4; ++r) {
    const int qA = qbaseA + h * 4 + r;
    const int qB = qbaseB + h * 4 + r;
    Opart[(obase0 + qA) * IC_ + q16]      = f2bf(aA0[r]);
    Opart[(obase0 + qA) * IC_ + 16 + q16] = f2bf(aA1[r]);
    Opart[(obase0 + qB) * IC_ + q16]      = f2bf(aB0[r]);
    Opart[(obase0 + qB) * IC_ + 16 + q16] = f2bf(aB1[r]);
  }
  if (q16 == 0) {
#pragma unroll
    for (int r = 0; r < 4; ++r) {
      Lp[obase0 + qbaseA + h * 4 + r] = aLA[r];
      Lp[obase0 + qbaseB + h * 4 + r] = aLB[r];
    }
  }
}

// ---------------------------------------------------------------------------
// Kernel 2b: combine partials. y[bn][d] = sum_s O_s[bn][d] / sum_s l_s[bn].
// 4 threads per bn (8 dims each). grid 288 x 256.
// ---------------------------------------------------------------------------
__global__ __launch_bounds__(256) void combine_kernel(
    const ushort* __restrict__ Opart, const float* __restrict__ Lp,
    float* __restrict__ Y)
{
  const int idx     = blockIdx.x * 256 + threadIdx.x;
  const int bn      = idx >> 2;
  const int quarter = idx & 3;
  const int b       = bn / N_;
  const int q       = bn % N_;

  float l = 0.f;
  float o[8];
#pragma unroll
  for (int j = 0; j < 8; ++j) o[j] = 0.f;

#pragma unroll
  for (int s = 0; s < SEG_; ++s) {
    const size_t base = (size_t)(b * SEG_ + s) * N_ + q;
    l += Lp[base];
    union { s16x8 v; ushort us[8]; } ov;
    ov.v = *reinterpret_cast<const s16x8*>(Opart + base * IC_ + quarter * 8);
#pragma unroll
    for (int j = 0; j < 8; ++j) o[j] += bf2f(ov.us[j]);
  }
  const float inv = 1.0f / l;
  f32x4 y0 = {o[0] * inv, o[1] * inv, o[2] * inv, o[3] * inv};
  f32x4 y1 = {o[4] * inv, o[5] * inv, o[6] * inv, o[7] * inv};
  f32x4* yp = reinterpret_cast<f32x4*>(Y + (size_t)bn * IC_ + quarter * 8);
  yp[0] = y0; yp[1] = y1;
}

// ---------------------------------------------------------------------------
// Kernel 3: o = Wo @ y + bo + x. grid: 4 oc-groups x 72 n-blocks, 256 thr.
// Thread: 16 oc, 1 bn. (Y re-read x4 instead of x16.)
// ---------------------------------------------------------------------------
__global__ __launch_bounds__(256) void out_kernel(
    const float* __restrict__ Y, const float* __restrict__ Wo,
    const float* __restrict__ bo, const float* __restrict__ x,
    float* __restrict__ out)
{
  const int g    = blockIdx.x / 72;   // oc group 0..3 (wave-uniform), 16 oc each
  const int oc0  = g * 16;
  const int bn   = (blockIdx.x % 72) * 256 + threadIdx.x;
  const int b    = bn / N_;
  const int n    = bn % N_;

  float yv[32];
#pragma unroll
  for (int i = 0; i < 8; ++i) {
    const f32x4 v = *reinterpret_cast<const f32x4*>(Y + (size_t)bn * IC_ + i * 4);
    yv[i * 4 + 0] = v[0]; yv[i * 4 + 1] = v[1];
    yv[i * 4 + 2] = v[2]; yv[i * 4 + 3] = v[3];
  }

  float acc[16];
#pragma unroll
  for (int j = 0; j < 16; ++j) acc[j] = bo[oc0 + j];

#pragma unroll
  for (int ic = 0; ic < IC_; ++ic) {
    const float yv_ic = yv[ic];
#pragma unroll
    for (int j = 0; j < 16; ++j)
      acc[j] = fmaf(Wo[(oc0 + j) * IC_ + ic], yv_ic, acc[j]);
  }

#pragma unroll
  for (int j = 0; j < 16; ++j) {
    const int oc = oc0 + j;
    const size_t xi = (size_t)(b * C_ + oc) * N_ + n;
    out[xi] = acc[j] + x[xi];
  }
}

// ---------------------------------------------------------------------------
extern "C" void kernel_launch(void* const* d_in, const int* in_sizes, int n_in,
                              void* d_out, int out_size, void* d_ws, size_t ws_size,
                              hipStream_t stream)
{
  const float* x  = (const float*)d_in[0];
  const float* Wg = (const float*)d_in[1];
  const float* bg = (const float*)d_in[2];
  const float* Wt = (const float*)d_in[3];
  const float* bt = (const float*)d_in[4];
  const float* Wp = (const float*)d_in[5];
  const float* bp = (const float*)d_in[6];
  const float* Wo = (const float*)d_in[7];
  const float* bo = (const float*)d_in[8];
  float* out = (float*)d_out;

  char* ws = (char*)d_ws;
  const size_t szb  = (size_t)B_ * N_ * IC_ * sizeof(ushort);        // 1,179,648 B
  const size_t szOp = (size_t)B_ * SEG_ * N_ * IC_ * sizeof(ushort); // 9,437,184 B
  ushort* Qb = (ushort*)(ws);                       // theta*log2e, bf16 [B][N][32]
  ushort* Kb = (ushort*)(ws + szb);                 // phi, bf16 [B][N][32]
  ushort* Vt = (ushort*)(ws + 2 * szb);             // g,   bf16 [B][32][N] (perm'd)
  ushort* Op = (ushort*)(ws + 3 * szb);             // partial O bf16 [B][S][N][32]
  float*  Lp = (float*)(ws + 3 * szb + szOp);       // partial l fp32 [B][S][N]
  // Y aliases Qb+Kb (2.36 MB): written by combine only after attn has finished
  // reading Q/K; rewritten by proj at the start of every launch.
  float*  Yw = (float*)(ws);

  proj_kernel<<<288, 256, 0, stream>>>(x, Wg, bg, Wt, bt, Wp, bp, Qb, Kb, Vt);
  attn_kernel<<<B_ * SEG_ * QBLK128, 256, 0, stream>>>(Qb, Kb, Vt, Op, Lp);
  combine_kernel<<<(B_ * N_ * 4) / 256, 256, 0, stream>>>(Op, Lp, Yw);
  out_kernel<<<4 * 72, 256, 0, stream>>>(Yw, Wo, bo, x, out);
}